// Round 3
// baseline (2385.050 us; speedup 1.0000x reference)
//
#include <hip/hip_runtime.h>
#include <hip/hip_bf16.h>
#include <math.h>

// Problem constants (from reference): D=3, H=64, WIN=8, OUT=32, B=128, T=129
#define DD 3
#define HH 64
#define WINW 8
#define OUTD 32
#define BB 128
#define TT 129
#define NSTEP 128
#define NW 16

__device__ __forceinline__ float softplus_f(float x) {
    return (x > 20.f) ? x : log1pf(expf(x));
}
__device__ __forceinline__ float sigmoid_f(float x) {
    return 1.f / (1.f + expf(-x));
}

// NOTE: macro params must not collide with float4 member names (.x/.y/.z/.w)
#define DOT4(acc, Wv, Av) acc += (Wv).x*(Av).x + (Wv).y*(Av).y + (Wv).z*(Av).z + (Wv).w*(Av).w

__global__ __launch_bounds__(256, 1)
void ncde_solve(const float* __restrict__ ts, const float* __restrict__ x,
                const float* __restrict__ W0, const float* __restrict__ b0,
                const float* __restrict__ W1, const float* __restrict__ b1,
                const float* __restrict__ W2, const float* __restrict__ b2,
                const float* __restrict__ V0, const float* __restrict__ c0,
                const float* __restrict__ V1, const float* __restrict__ c1,
                const float* __restrict__ V2, const float* __restrict__ c2,
                const float* __restrict__ R, const float* __restrict__ rb,
                float* __restrict__ out)
{
    const int b = blockIdx.x;
    const int tid = threadIdx.x;

    __shared__ float RSh[OUTD*HH];
    __shared__ float a0Sh[128], a1Sh[128], sig0Sh[128], sig1Sh[128];
    __shared__ float mSh[192], dtanSh[192];
    __shared__ float u0Sh[3][128], u1Sh[3][128];
    __shared__ float JfSh[3][192];
    __shared__ float ySh[64], y2Sh[64], k1Sh[64], k2Sh[64];
    __shared__ float slopesSh[NW][6];
    __shared__ float dtsSh[NSTEP];

    // ---- per-thread weight rows in registers ----
    // t<128: V0 row t (64 f), V1 row t (128 f); t<192: V2 row t (128 f)
    float4 v0r[16]; float4 v1r[32]; float4 v2r[32];
    if (tid < 128) {
        const float4* p0 = (const float4*)(V0 + tid*64);
        #pragma unroll
        for (int k=0;k<16;k++) v0r[k] = p0[k];
        const float4* p1 = (const float4*)(V1 + tid*128);
        #pragma unroll
        for (int k=0;k<32;k++) v1r[k] = p1[k];
    }
    if (tid < 192) {
        const float4* p2 = (const float4*)(V2 + tid*128);
        #pragma unroll
        for (int k=0;k<32;k++) v2r[k] = p2[k];
    }
    const float c0r = (tid<128) ? c0[tid] : 0.f;
    const float c1r = (tid<128) ? c1[tid] : 0.f;
    const float c2r = (tid<192) ? c2[tid] : 0.f;
    const float rbr = (tid<OUTD) ? rb[tid] : 0.f;

    for (int i = tid; i < OUTD*HH; i += 256) RSh[i] = R[i];
    const float* tsb = ts + b*TT;
    for (int i = tid; i < NSTEP; i += 256) dtsSh[i] = tsb[i+1] - tsb[i];

    // ---- log-signature slopes (one thread per window) ----
    if (tid < NW) {
        const int w = tid;
        const float* xs = x + (size_t)(b*TT + w*WINW)*DD;
        float x0c[3] = {xs[0], xs[1], xs[2]};
        float prev[3] = {x0c[0], x0c[1], x0c[2]};
        float am[3][3] = {{0,0,0},{0,0,0},{0,0,0}};
        #pragma unroll
        for (int k=0;k<WINW;k++) {
            float cur[3] = {xs[(k+1)*3+0], xs[(k+1)*3+1], xs[(k+1)*3+2]};
            float rel[3], dv[3];
            #pragma unroll
            for (int c=0;c<3;c++){ rel[c]=prev[c]-x0c[c]; dv[c]=cur[c]-prev[c]; }
            #pragma unroll
            for (int i2=0;i2<3;i2++)
                #pragma unroll
                for (int j2=0;j2<3;j2++) am[i2][j2] += rel[i2]*dv[j2];
            prev[0]=cur[0]; prev[1]=cur[1]; prev[2]=cur[2];
        }
        const float invden = 1.f/(tsb[(w+1)*WINW] - tsb[w*WINW]);
        slopesSh[w][0] = (prev[0]-x0c[0])*invden;
        slopesSh[w][1] = (prev[1]-x0c[1])*invden;
        slopesSh[w][2] = (prev[2]-x0c[2])*invden;
        slopesSh[w][3] = 0.5f*(am[0][1]-am[1][0])*invden;
        slopesSh[w][4] = 0.5f*(am[0][2]-am[2][0])*invden;
        slopesSh[w][5] = 0.5f*(am[1][2]-am[2][1])*invden;
    }

    // ---- h0 = init_mlp(x[b,0,:]) ----
    if (tid < 128) {
        const float xv0 = x[(size_t)b*TT*DD+0];
        const float xv1 = x[(size_t)b*TT*DD+1];
        const float xv2 = x[(size_t)b*TT*DD+2];
        float acc = b0[tid] + W0[tid*3]*xv0 + W0[tid*3+1]*xv1 + W0[tid*3+2]*xv2;
        a0Sh[tid] = softplus_f(acc);
    }
    __syncthreads();
    if (tid < 128) {
        float acc = b1[tid];
        const float4* r = (const float4*)(W1 + tid*128);
        #pragma unroll 8
        for (int k=0;k<32;k++){ float4 wv=r[k]; float4 av=*(const float4*)&a0Sh[4*k]; DOT4(acc,wv,av); }
        a1Sh[tid] = softplus_f(acc);
    }
    __syncthreads();
    if (tid < 64) {
        float acc = b2[tid];
        const float4* r = (const float4*)(W2 + tid*128);
        #pragma unroll 8
        for (int k=0;k<32;k++){ float4 wv=r[k]; float4 av=*(const float4*)&a1Sh[4*k]; DOT4(acc,wv,av); }
        ySh[tid] = acc;
    }
    __syncthreads();
    if (tid < OUTD) {
        float acc = rbr;
        #pragma unroll
        for (int k=0;k<16;k++){ float4 rv=*(const float4*)&RSh[tid*HH+4*k]; float4 yv=*(const float4*)&ySh[4*k]; DOT4(acc,rv,yv); }
        out[(size_t)(b*TT+0)*OUTD + tid] = tanhf(acc);
    }
    __syncthreads();

    // ---- F(y) -> k, fp32, weights from registers, activations via LDS ----
    auto Feval = [&](const float* yIn, float* kOut,
                     float s0,float s1,float s2,float s3,float s4,float s5) {
        // S1: z0 = V0@y + c0 ; a0 = sp(z0), sig0
        if (tid < 128) {
            float acc = c0r;
            #pragma unroll
            for (int k=0;k<16;k++){ float4 av=*(const float4*)&yIn[4*k]; DOT4(acc,v0r[k],av); }
            a0Sh[tid] = softplus_f(acc);
            sig0Sh[tid] = sigmoid_f(acc);
        }
        __syncthreads();
        // S2: z1 = V1@a0 + c1 ; a1 = sp, sig1
        if (tid < 128) {
            float acc = c1r;
            #pragma unroll
            for (int k=0;k<32;k++){ float4 av=*(const float4*)&a0Sh[4*k]; DOT4(acc,v1r[k],av); }
            a1Sh[tid] = softplus_f(acc);
            sig1Sh[tid] = sigmoid_f(acc);
        }
        __syncthreads();
        // S3: z2 = V2@a1 + c2 ; m = tanh, dtan = 1-m^2
        if (tid < 192) {
            float acc = c2r;
            #pragma unroll
            for (int k=0;k<32;k++){ float4 av=*(const float4*)&a1Sh[4*k]; DOT4(acc,v2r[k],av); }
            float mm = tanhf(acc);
            mSh[tid] = mm;
            dtanSh[tid] = 1.f - mm*mm;
        }
        __syncthreads();
        // S4: tangents d=0..2: u0[d] = sig0 * (V0 @ m[d*64..])
        if (tid < 128) {
            float t0=0.f,t1=0.f,t2=0.f;
            #pragma unroll
            for (int k=0;k<16;k++){
                float4 wv=v0r[k];
                float4 m0=*(const float4*)&mSh[4*k];
                float4 m1=*(const float4*)&mSh[64+4*k];
                float4 m2=*(const float4*)&mSh[128+4*k];
                DOT4(t0,wv,m0); DOT4(t1,wv,m1); DOT4(t2,wv,m2);
            }
            const float sg = sig0Sh[tid];
            u0Sh[0][tid]=sg*t0; u0Sh[1][tid]=sg*t1; u0Sh[2][tid]=sg*t2;
        }
        __syncthreads();
        // S5: u1[d] = sig1 * (V1 @ u0[d])
        if (tid < 128) {
            float t0=0.f,t1=0.f,t2=0.f;
            #pragma unroll
            for (int k=0;k<32;k++){
                float4 wv=v1r[k];
                float4 q0=*(const float4*)&u0Sh[0][4*k];
                float4 q1=*(const float4*)&u0Sh[1][4*k];
                float4 q2=*(const float4*)&u0Sh[2][4*k];
                DOT4(t0,wv,q0); DOT4(t1,wv,q1); DOT4(t2,wv,q2);
            }
            const float sg = sig1Sh[tid];
            u1Sh[0][tid]=sg*t0; u1Sh[1][tid]=sg*t1; u1Sh[2][tid]=sg*t2;
        }
        __syncthreads();
        // S6: Jf[d] = dtan * (V2 @ u1[d])
        if (tid < 192) {
            float t0=0.f,t1=0.f,t2=0.f;
            #pragma unroll
            for (int k=0;k<32;k++){
                float4 wv=v2r[k];
                float4 q0=*(const float4*)&u1Sh[0][4*k];
                float4 q1=*(const float4*)&u1Sh[1][4*k];
                float4 q2=*(const float4*)&u1Sh[2][4*k];
                DOT4(t0,wv,q0); DOT4(t1,wv,q1); DOT4(t2,wv,q2);
            }
            const float dd = dtanSh[tid];
            JfSh[0][tid]=dd*t0; JfSh[1][tid]=dd*t1; JfSh[2][tid]=dd*t2;
        }
        __syncthreads();
        // S7: k[h] = sum_c m[c,h]*s_c + sum_p s_{3+p}*(J[iu][ju,h]-J[ju][iu,h])
        if (tid < 64) {
            const int h = tid;
            float kk = mSh[h]*s0 + mSh[64+h]*s1 + mSh[128+h]*s2;
            kk += s3*(JfSh[0][64+h]  - JfSh[1][h]);        // pair (0,1)
            kk += s4*(JfSh[0][128+h] - JfSh[2][h]);        // pair (0,2)
            kk += s5*(JfSh[1][128+h] - JfSh[2][64+h]);     // pair (1,2)
            kOut[h] = kk;
        }
        __syncthreads();
    };

    // ---- Heun scan over 128 steps ----
    for (int step=0; step<NSTEP; ++step) {
        const int w = step >> 3;
        const float s0=slopesSh[w][0], s1=slopesSh[w][1], s2=slopesSh[w][2],
                    s3=slopesSh[w][3], s4=slopesSh[w][4], s5=slopesSh[w][5];
        const float dt = dtsSh[step];
        Feval(ySh, k1Sh, s0,s1,s2,s3,s4,s5);
        if (tid < 64) y2Sh[tid] = ySh[tid] + dt*k1Sh[tid];
        __syncthreads();
        Feval(y2Sh, k2Sh, s0,s1,s2,s3,s4,s5);
        if (tid < 64) ySh[tid] += 0.5f*dt*(k1Sh[tid]+k2Sh[tid]);
        __syncthreads();
        // output projection for row step+1 (reads-only; next Feval writes disjoint arrays)
        if (tid < OUTD) {
            float acc = rbr;
            #pragma unroll
            for (int k=0;k<16;k++){ float4 rv=*(const float4*)&RSh[tid*HH+4*k]; float4 yv=*(const float4*)&ySh[4*k]; DOT4(acc,rv,yv); }
            out[(size_t)(b*TT + step+1)*OUTD + tid] = tanhf(acc);
        }
    }
}

extern "C" void kernel_launch(void* const* d_in, const int* in_sizes, int n_in,
                              void* d_out, int out_size, void* d_ws, size_t ws_size,
                              hipStream_t stream) {
    const float* ts = (const float*)d_in[0];
    const float* x  = (const float*)d_in[1];
    const float* W0 = (const float*)d_in[2];
    const float* b0 = (const float*)d_in[3];
    const float* W1 = (const float*)d_in[4];
    const float* b1 = (const float*)d_in[5];
    const float* W2 = (const float*)d_in[6];
    const float* b2 = (const float*)d_in[7];
    const float* V0 = (const float*)d_in[8];
    const float* c0 = (const float*)d_in[9];
    const float* V1 = (const float*)d_in[10];
    const float* c1 = (const float*)d_in[11];
    const float* V2 = (const float*)d_in[12];
    const float* c2 = (const float*)d_in[13];
    const float* R  = (const float*)d_in[14];
    const float* rb = (const float*)d_in[15];
    float* out = (float*)d_out;

    ncde_solve<<<dim3(BB), dim3(256), 0, stream>>>(
        ts, x, W0, b0, W1, b1, W2, b2, V0, c0, V1, c1, V2, c2, R, rb, out);
}

// Round 4
// 1926.222 us; speedup vs baseline: 1.2382x; 1.2382x over previous
//
#include <hip/hip_runtime.h>
#include <math.h>

// Problem constants: D=3, H=64, WIN=8, OUT=32, B=128, T=129
#define DD 3
#define HH 64
#define WINW 8
#define OUTD 32
#define BB 128
#define TT 129
#define NSTEP 128
#define NW 16

#define DOT4(acc, Wv, Av) acc += (Wv).x*(Av).x + (Wv).y*(Av).y + (Wv).z*(Av).z + (Wv).w*(Av).w

__device__ __forceinline__ float fast_rcp(float v) { return __builtin_amdgcn_rcpf(v); }
__device__ __forceinline__ float softplus_f(float v) {
    // max(x,0) + log1p(exp(-|x|)) with HW exp/log; |err| ~1e-7 rel
    return fmaxf(v, 0.f) + __logf(1.f + __expf(-fabsf(v)));
}
__device__ __forceinline__ float sigmoid_f(float v) {
    return fast_rcp(1.f + __expf(-v));
}
__device__ __forceinline__ float tanh_f(float v) {
    float ax = fminf(fabsf(v), 15.f);
    float e  = __expf(2.f * ax);
    float r  = 1.f - 2.f * fast_rcp(e + 1.f);
    return copysignf(r, v);
}

__global__ __launch_bounds__(256, 1)
void ncde_solve(const float* __restrict__ ts, const float* __restrict__ x,
                const float* __restrict__ W0, const float* __restrict__ b0,
                const float* __restrict__ W1, const float* __restrict__ b1,
                const float* __restrict__ W2, const float* __restrict__ b2,
                const float* __restrict__ V0, const float* __restrict__ c0,
                const float* __restrict__ V1, const float* __restrict__ c1,
                const float* __restrict__ V2, const float* __restrict__ c2,
                const float* __restrict__ R, const float* __restrict__ rb,
                float* __restrict__ out)
{
    const int b = blockIdx.x;
    const int tid = threadIdx.x;
    // 128-row stages: (row, K-half)
    const int row2 = tid >> 1, half = tid & 1;
    // V2 upper 64 rows: (row, K-quarter)
    const int row4 = 128 + (tid >> 2), quad = tid & 3;
    // projection: (row, K-eighth)
    const int prow = tid >> 3, poct = tid & 7;

    __shared__ float RSh[OUTD*HH];
    __shared__ float a0Sh[128], sig0Sh[128], a1Sh[128], sig1Sh[128];
    __shared__ float mSh[192], dtanSh[192];
    __shared__ float u0Sh[3][128], u1Sh[3][128];
    __shared__ float JfSh[3][192];
    __shared__ float ySh[64], y2Sh[64], k1Sh[64];
    __shared__ float slopesSh[NW][6];
    __shared__ float dtsSh[NSTEP];

    // ---- per-thread HALF/QUARTER weight rows in registers (192 VGPRs total) ----
    float4 v0h[8], v1h[16], v2h[16], v2q[8];
    {
        const float4* p0 = (const float4*)(V0 + row2*64 + half*32);
        #pragma unroll
        for (int k=0;k<8;k++)  v0h[k] = p0[k];
        const float4* p1 = (const float4*)(V1 + row2*128 + half*64);
        #pragma unroll
        for (int k=0;k<16;k++) v1h[k] = p1[k];
        const float4* p2 = (const float4*)(V2 + row2*128 + half*64);
        #pragma unroll
        for (int k=0;k<16;k++) v2h[k] = p2[k];
        // rotated quarter-block order: inst j reads f4 index quad*8+((quad+j)&7)
        const float* p3 = V2 + row4*128;
        #pragma unroll
        for (int j=0;j<8;j++) {
            int idx = quad*8 + ((quad + j) & 7);
            v2q[j] = *(const float4*)(p3 + idx*4);
        }
    }
    const float c0r = c0[row2], c1r = c1[row2], c2a = c2[row2], c2b = c2[row4];
    const float rbp = rb[prow];

    for (int i=tid; i<OUTD*HH; i+=256) RSh[i] = R[i];
    const float* tsb = ts + b*TT;
    for (int i=tid; i<NSTEP; i+=256) dtsSh[i] = tsb[i+1] - tsb[i];

    // ---- log-signature slopes (one thread per window) ----
    if (tid < NW) {
        const int w = tid;
        const float* xs = x + (size_t)(b*TT + w*WINW)*DD;
        float x0c[3] = {xs[0], xs[1], xs[2]};
        float prev[3] = {x0c[0], x0c[1], x0c[2]};
        float am01=0.f, am02=0.f, am12=0.f, am10=0.f, am20=0.f, am21=0.f;
        #pragma unroll
        for (int k=0;k<WINW;k++) {
            float cur[3] = {xs[(k+1)*3+0], xs[(k+1)*3+1], xs[(k+1)*3+2]};
            float rel[3], dv[3];
            #pragma unroll
            for (int c=0;c<3;c++){ rel[c]=prev[c]-x0c[c]; dv[c]=cur[c]-prev[c]; }
            am01 += rel[0]*dv[1]; am10 += rel[1]*dv[0];
            am02 += rel[0]*dv[2]; am20 += rel[2]*dv[0];
            am12 += rel[1]*dv[2]; am21 += rel[2]*dv[1];
            prev[0]=cur[0]; prev[1]=cur[1]; prev[2]=cur[2];
        }
        const float invden = 1.f/(tsb[(w+1)*WINW] - tsb[w*WINW]);
        slopesSh[w][0] = (prev[0]-x0c[0])*invden;
        slopesSh[w][1] = (prev[1]-x0c[1])*invden;
        slopesSh[w][2] = (prev[2]-x0c[2])*invden;
        slopesSh[w][3] = 0.5f*(am01-am10)*invden;
        slopesSh[w][4] = 0.5f*(am02-am20)*invden;
        slopesSh[w][5] = 0.5f*(am12-am21)*invden;
    }

    // ---- h0 = init_mlp(x[b,0,:]) (one-time, global-streamed weights) ----
    if (tid < 128) {
        const float xv0 = x[(size_t)b*TT*DD+0];
        const float xv1 = x[(size_t)b*TT*DD+1];
        const float xv2 = x[(size_t)b*TT*DD+2];
        float acc = b0[tid] + W0[tid*3]*xv0 + W0[tid*3+1]*xv1 + W0[tid*3+2]*xv2;
        a0Sh[tid] = softplus_f(acc);
    }
    __syncthreads();
    if (tid < 128) {
        float acc = b1[tid];
        const float4* r = (const float4*)(W1 + tid*128);
        #pragma unroll 8
        for (int k=0;k<32;k++){ float4 wv=r[k]; float4 av=*(const float4*)&a0Sh[4*k]; DOT4(acc,wv,av); }
        a1Sh[tid] = softplus_f(acc);
    }
    __syncthreads();
    if (tid < 64) {
        float acc = b2[tid];
        const float4* r = (const float4*)(W2 + tid*128);
        #pragma unroll 8
        for (int k=0;k<32;k++){ float4 wv=r[k]; float4 av=*(const float4*)&a1Sh[4*k]; DOT4(acc,wv,av); }
        ySh[tid] = acc;
    }
    __syncthreads();

    // ---- F(y): all 256 lanes active in every large stage ----
    auto Feval = [&](const float* yIn, bool first, float dt, int w) {
        // S1: z0 = V0@y + c0
        {
            float zA=0.f, zB=0.f;
            const float4* yb = (const float4*)(yIn + half*32);
            #pragma unroll
            for (int k=0;k<4;k++){ DOT4(zA, v0h[k], yb[k]); }
            #pragma unroll
            for (int k=4;k<8;k++){ DOT4(zB, v0h[k], yb[k]); }
            float z = zA + zB;
            z += __shfl_xor(z, 1, 64);
            z += c0r;
            if (!half){ a0Sh[row2] = softplus_f(z); sig0Sh[row2] = sigmoid_f(z); }
        }
        __syncthreads();
        // S2: z1 = V1@a0 + c1
        {
            float zA=0.f, zB=0.f;
            const float4* ab = (const float4*)(a0Sh + half*64);
            #pragma unroll
            for (int k=0;k<8;k++){  DOT4(zA, v1h[k], ab[k]); }
            #pragma unroll
            for (int k=8;k<16;k++){ DOT4(zB, v1h[k], ab[k]); }
            float z = zA + zB;
            z += __shfl_xor(z, 1, 64);
            z += c1r;
            if (!half){ a1Sh[row2] = softplus_f(z); sig1Sh[row2] = sigmoid_f(z); }
        }
        __syncthreads();
        // S3: z2 = V2@a1 + c2 ; m = tanh(z2), dtan = 1-m^2   (192 rows: 128 half-split + 64 quarter-split)
        {
            float zA=0.f, zB=0.f;
            const float4* ab = (const float4*)(a1Sh + half*64);
            #pragma unroll
            for (int k=0;k<8;k++){  DOT4(zA, v2h[k], ab[k]); }
            #pragma unroll
            for (int k=8;k<16;k++){ DOT4(zB, v2h[k], ab[k]); }
            float z = zA + zB;
            z += __shfl_xor(z, 1, 64);
            z += c2a;
            if (!half){ float mm=tanh_f(z); mSh[row2]=mm; dtanSh[row2]=1.f-mm*mm; }

            float zq = 0.f;
            const float4* a4 = (const float4*)a1Sh;
            #pragma unroll
            for (int j=0;j<8;j++){ DOT4(zq, v2q[j], a4[quad*8 + ((quad+j)&7)]); }
            zq += __shfl_xor(zq, 1, 64);
            zq += __shfl_xor(zq, 2, 64);
            zq += c2b;
            if (!quad){ float mm=tanh_f(zq); mSh[row4]=mm; dtanSh[row4]=1.f-mm*mm; }
        }
        __syncthreads();
        // S4: u0[d] = sig0 * (V0 @ m[d])
        {
            float t0=0.f,t1=0.f,t2=0.f;
            const float4* m0 = (const float4*)(mSh       + half*32);
            const float4* m1 = (const float4*)(mSh + 64  + half*32);
            const float4* m2 = (const float4*)(mSh + 128 + half*32);
            #pragma unroll
            for (int k=0;k<8;k++){ DOT4(t0,v0h[k],m0[k]); DOT4(t1,v0h[k],m1[k]); DOT4(t2,v0h[k],m2[k]); }
            t0 += __shfl_xor(t0,1,64);
            t1 += __shfl_xor(t1,1,64);
            t2 += __shfl_xor(t2,1,64);
            if (!half){
                float sg = sig0Sh[row2];
                u0Sh[0][row2]=sg*t0; u0Sh[1][row2]=sg*t1; u0Sh[2][row2]=sg*t2;
            }
        }
        __syncthreads();
        // S5: u1[d] = sig1 * (V1 @ u0[d])
        {
            float t0=0.f,t1=0.f,t2=0.f;
            const float4* q0 = (const float4*)(&u0Sh[0][0] + half*64);
            const float4* q1 = (const float4*)(&u0Sh[1][0] + half*64);
            const float4* q2 = (const float4*)(&u0Sh[2][0] + half*64);
            #pragma unroll
            for (int k=0;k<16;k++){ DOT4(t0,v1h[k],q0[k]); DOT4(t1,v1h[k],q1[k]); DOT4(t2,v1h[k],q2[k]); }
            t0 += __shfl_xor(t0,1,64);
            t1 += __shfl_xor(t1,1,64);
            t2 += __shfl_xor(t2,1,64);
            if (!half){
                float sg = sig1Sh[row2];
                u1Sh[0][row2]=sg*t0; u1Sh[1][row2]=sg*t1; u1Sh[2][row2]=sg*t2;
            }
        }
        __syncthreads();
        // S6: Jf[d] = dtan * (V2 @ u1[d])
        {
            float t0=0.f,t1=0.f,t2=0.f;
            const float4* q0 = (const float4*)(&u1Sh[0][0] + half*64);
            const float4* q1 = (const float4*)(&u1Sh[1][0] + half*64);
            const float4* q2 = (const float4*)(&u1Sh[2][0] + half*64);
            #pragma unroll
            for (int k=0;k<16;k++){ DOT4(t0,v2h[k],q0[k]); DOT4(t1,v2h[k],q1[k]); DOT4(t2,v2h[k],q2[k]); }
            t0 += __shfl_xor(t0,1,64);
            t1 += __shfl_xor(t1,1,64);
            t2 += __shfl_xor(t2,1,64);
            if (!half){
                float dd = dtanSh[row2];
                JfSh[0][row2]=dd*t0; JfSh[1][row2]=dd*t1; JfSh[2][row2]=dd*t2;
            }
            float s0=0.f,s1=0.f,s2=0.f;
            const float4* w0 = (const float4*)&u1Sh[0][0];
            const float4* w1 = (const float4*)&u1Sh[1][0];
            const float4* w2 = (const float4*)&u1Sh[2][0];
            #pragma unroll
            for (int j=0;j<8;j++){
                const int idx = quad*8 + ((quad+j)&7);
                DOT4(s0,v2q[j],w0[idx]); DOT4(s1,v2q[j],w1[idx]); DOT4(s2,v2q[j],w2[idx]);
            }
            s0 += __shfl_xor(s0,1,64); s0 += __shfl_xor(s0,2,64);
            s1 += __shfl_xor(s1,1,64); s1 += __shfl_xor(s1,2,64);
            s2 += __shfl_xor(s2,1,64); s2 += __shfl_xor(s2,2,64);
            if (!quad){
                float dd = dtanSh[row4];
                JfSh[0][row4]=dd*s0; JfSh[1][row4]=dd*s1; JfSh[2][row4]=dd*s2;
            }
        }
        __syncthreads();
        // S7 + Heun integrate (64 lanes, tiny)
        if (tid < 64) {
            const int h = tid;
            const float s0=slopesSh[w][0], s1=slopesSh[w][1], s2=slopesSh[w][2],
                        s3=slopesSh[w][3], s4=slopesSh[w][4], s5=slopesSh[w][5];
            float kk = mSh[h]*s0 + mSh[64+h]*s1 + mSh[128+h]*s2;
            kk += s3*(JfSh[0][64+h]  - JfSh[1][h]);
            kk += s4*(JfSh[0][128+h] - JfSh[2][h]);
            kk += s5*(JfSh[1][128+h] - JfSh[2][64+h]);
            if (first){ k1Sh[h] = kk; y2Sh[h] = ySh[h] + dt*kk; }
            else      { ySh[h] = ySh[h] + 0.5f*dt*(k1Sh[h] + kk); }
        }
        __syncthreads();
    };

    // ---- Heun scan; projection of y_step fused into Feval1's first phase ----
    for (int step=0; step<NSTEP; ++step) {
        {   // out row `step` = tanh(R @ ySh + rb)   (reads-only; same phase as S1)
            float pacc = 0.f;
            const float4* rr = (const float4*)(RSh + prow*64 + poct*8);
            const float4* yy = (const float4*)(ySh + poct*8);
            DOT4(pacc, rr[0], yy[0]); DOT4(pacc, rr[1], yy[1]);
            pacc += __shfl_xor(pacc,1,64);
            pacc += __shfl_xor(pacc,2,64);
            pacc += __shfl_xor(pacc,4,64);
            if (!poct) out[(size_t)(b*TT + step)*OUTD + prow] = tanh_f(pacc + rbp);
        }
        const float dt = dtsSh[step];
        const int w = step >> 3;
        Feval(ySh,  true,  dt, w);
        Feval(y2Sh, false, dt, w);
    }
    // final row 128
    {
        float pacc = 0.f;
        const float4* rr = (const float4*)(RSh + prow*64 + poct*8);
        const float4* yy = (const float4*)(ySh + poct*8);
        DOT4(pacc, rr[0], yy[0]); DOT4(pacc, rr[1], yy[1]);
        pacc += __shfl_xor(pacc,1,64);
        pacc += __shfl_xor(pacc,2,64);
        pacc += __shfl_xor(pacc,4,64);
        if (!poct) out[(size_t)(b*TT + NSTEP)*OUTD + prow] = tanh_f(pacc + rbp);
    }
}

extern "C" void kernel_launch(void* const* d_in, const int* in_sizes, int n_in,
                              void* d_out, int out_size, void* d_ws, size_t ws_size,
                              hipStream_t stream) {
    const float* ts = (const float*)d_in[0];
    const float* x  = (const float*)d_in[1];
    const float* W0 = (const float*)d_in[2];
    const float* b0 = (const float*)d_in[3];
    const float* W1 = (const float*)d_in[4];
    const float* b1 = (const float*)d_in[5];
    const float* W2 = (const float*)d_in[6];
    const float* b2 = (const float*)d_in[7];
    const float* V0 = (const float*)d_in[8];
    const float* c0 = (const float*)d_in[9];
    const float* V1 = (const float*)d_in[10];
    const float* c1 = (const float*)d_in[11];
    const float* V2 = (const float*)d_in[12];
    const float* c2 = (const float*)d_in[13];
    const float* R  = (const float*)d_in[14];
    const float* rb = (const float*)d_in[15];
    float* out = (float*)d_out;

    ncde_solve<<<dim3(BB), dim3(256), 0, stream>>>(
        ts, x, W0, b0, W1, b1, W2, b2, V0, c0, V1, c1, V2, c2, R, rb, out);
}

// Round 5
// 907.790 us; speedup vs baseline: 2.6273x; 2.1219x over previous
//
#include <hip/hip_runtime.h>
#include <math.h>

// Problem constants: D=3, H=64, WIN=8, OUT=32, B=128, T=129
#define BB 128
#define TT 129
#define NSTEP 128
#define NW 16
#define WINW 8
#define OUTD 32

typedef _Float16 h2_t __attribute__((ext_vector_type(2)));

__device__ __forceinline__ float fast_rcp(float v){ return __builtin_amdgcn_rcpf(v); }
__device__ __forceinline__ float softplus_f(float v){ return fmaxf(v,0.f)+__logf(1.f+__expf(-fabsf(v))); }
__device__ __forceinline__ float sigmoid_f(float v){ return fast_rcp(1.f+__expf(-v)); }
__device__ __forceinline__ float tanh_f(float v){
    float ax=fminf(fabsf(v),15.f); float e=__expf(2.f*ax);
    float r=1.f-2.f*fast_rcp(e+1.f); return copysignf(r,v);
}

__device__ __forceinline__ float pack2(float a,float b){
    h2_t h; h.x=(_Float16)a; h.y=(_Float16)b; return __builtin_bit_cast(float,h);
}
__device__ __forceinline__ float dot2c(float wc,float ac,float acc){
#if __has_builtin(__builtin_amdgcn_fdot2)
    return __builtin_amdgcn_fdot2(__builtin_bit_cast(h2_t,wc),__builtin_bit_cast(h2_t,ac),acc,false);
#else
    h2_t w=__builtin_bit_cast(h2_t,wc), a=__builtin_bit_cast(h2_t,ac);
    return acc+(float)w.x*(float)a.x+(float)w.y*(float)a.y;
#endif
}
__device__ __forceinline__ float dot2q(float4 wq,float4 aq,float acc){
    acc=dot2c(wq.x,aq.x,acc); acc=dot2c(wq.y,aq.y,acc);
    acc=dot2c(wq.z,aq.z,acc); acc=dot2c(wq.w,aq.w,acc); return acc;
}
#define DOT4(acc,Wv,Av) acc += (Wv).x*(Av).x + (Wv).y*(Av).y + (Wv).z*(Av).z + (Wv).w*(Av).w
// pin a float4's components into VGPRs as asm-opaque values: no remat, no re-load
#define PIN4(q) asm volatile("" : "+v"((q).x), "+v"((q).y), "+v"((q).z), "+v"((q).w))

__global__ __launch_bounds__(256, 1)
void ncde_solve(const float* __restrict__ ts, const float* __restrict__ x,
                const float* __restrict__ W0, const float* __restrict__ b0,
                const float* __restrict__ W1, const float* __restrict__ b1,
                const float* __restrict__ W2, const float* __restrict__ b2,
                const float* __restrict__ V0, const float* __restrict__ c0,
                const float* __restrict__ V1, const float* __restrict__ c1,
                const float* __restrict__ V2, const float* __restrict__ c2,
                const float* __restrict__ R, const float* __restrict__ rb,
                float* __restrict__ out)
{
    const int b = blockIdx.x;
    const int tid = threadIdx.x;
    const int row2 = tid >> 1, half = tid & 1;       // 128-row stages, K halved
    const int row4 = 128 + (tid >> 2), quad = tid & 3; // V2 upper 64 rows, K quartered
    const int prow = tid >> 3, poct = tid & 7;        // projection

    __shared__ __align__(16) float RSh[OUTD*64];
    __shared__ __align__(16) float ySh[64], y2Sh[64], k1Sh[64];
    __shared__ __align__(16) float a0p[64], a1p[64];       // half2 carriers (128 halves)
    __shared__ __align__(16) float mp[96];                 // half2 carriers of m (192 halves)
    __shared__ __align__(16) float u0p[3][64], u1p[3][64]; // half2 carriers
    __shared__ float sig0Sh[128], sig1Sh[128];
    __shared__ float mSh[192], dtanSh[192];
    __shared__ float JfSh[3][192];
    __shared__ float slopesSh[NW][6];
    __shared__ float dtsSh[NSTEP];

    // ---- weights: fp32 V0 half-row (feedback path) + fp16 carriers, all register-pinned ----
    float4 v0f[8];   // V0 half-row fp32 (32 regs)
    float4 v0p4[4];  // V0 half-row f16 carriers (16)
    float4 v1p4[8];  // V1 half-row f16 (32)
    float4 v2p4[8];  // V2 (rows 0..127) half-row f16 (32)
    float4 v2q4[4];  // V2 (rows 128..191) quarter-row f16, rotated (16)
    {
        const float4* p0 = (const float4*)(V0 + row2*64 + half*32);
        #pragma unroll
        for (int k=0;k<8;k++) v0f[k] = p0[k];
        #pragma unroll
        for (int k=0;k<4;k++){
            float4 a=v0f[2*k], c=v0f[2*k+1];
            float4 r; r.x=pack2(a.x,a.y); r.y=pack2(a.z,a.w); r.z=pack2(c.x,c.y); r.w=pack2(c.z,c.w);
            v0p4[k]=r;
        }
        const float4* p1 = (const float4*)(V1 + row2*128 + half*64);
        #pragma unroll
        for (int k=0;k<8;k++){
            float4 a=p1[2*k], c=p1[2*k+1];
            float4 r; r.x=pack2(a.x,a.y); r.y=pack2(a.z,a.w); r.z=pack2(c.x,c.y); r.w=pack2(c.z,c.w);
            v1p4[k]=r;
        }
        const float4* p2 = (const float4*)(V2 + row2*128 + half*64);
        #pragma unroll
        for (int k=0;k<8;k++){
            float4 a=p2[2*k], c=p2[2*k+1];
            float4 r; r.x=pack2(a.x,a.y); r.y=pack2(a.z,a.w); r.z=pack2(c.x,c.y); r.w=pack2(c.z,c.w);
            v2q4[0]=v2q4[0]; // no-op
            v2p4[k]=r;
        }
        #pragma unroll
        for (int j=0;j<4;j++){
            int g=(quad+j)&3;
            const float4* pg = (const float4*)(V2 + row4*128 + quad*32 + g*8);
            float4 a=pg[0], c=pg[1];
            float4 r; r.x=pack2(a.x,a.y); r.y=pack2(a.z,a.w); r.z=pack2(c.x,c.y); r.w=pack2(c.z,c.w);
            v2q4[j]=r;
        }
        #pragma unroll
        for (int k=0;k<8;k++) PIN4(v0f[k]);
        #pragma unroll
        for (int k=0;k<4;k++) PIN4(v0p4[k]);
        #pragma unroll
        for (int k=0;k<8;k++) PIN4(v1p4[k]);
        #pragma unroll
        for (int k=0;k<8;k++) PIN4(v2p4[k]);
        #pragma unroll
        for (int k=0;k<4;k++) PIN4(v2q4[k]);
    }
    const float c0r = c0[row2], c1r = c1[row2], c2a = c2[row2], c2b = c2[row4];
    const float rbp = rb[prow];

    for (int i=tid; i<OUTD*64; i+=256) RSh[i] = R[i];
    const float* tsb = ts + b*TT;
    for (int i=tid; i<NSTEP; i+=256) dtsSh[i] = tsb[i+1] - tsb[i];

    // ---- log-signature slopes ----
    if (tid < NW) {
        const int w = tid;
        const float* xs = x + (size_t)(b*TT + w*WINW)*3;
        float x0c[3] = {xs[0], xs[1], xs[2]};
        float prev[3] = {x0c[0], x0c[1], x0c[2]};
        float am01=0.f, am02=0.f, am12=0.f, am10=0.f, am20=0.f, am21=0.f;
        #pragma unroll
        for (int k=0;k<WINW;k++) {
            float cur[3] = {xs[(k+1)*3+0], xs[(k+1)*3+1], xs[(k+1)*3+2]};
            float rel[3], dv[3];
            #pragma unroll
            for (int c=0;c<3;c++){ rel[c]=prev[c]-x0c[c]; dv[c]=cur[c]-prev[c]; }
            am01 += rel[0]*dv[1]; am10 += rel[1]*dv[0];
            am02 += rel[0]*dv[2]; am20 += rel[2]*dv[0];
            am12 += rel[1]*dv[2]; am21 += rel[2]*dv[1];
            prev[0]=cur[0]; prev[1]=cur[1]; prev[2]=cur[2];
        }
        const float invden = 1.f/(tsb[(w+1)*WINW] - tsb[w*WINW]);
        slopesSh[w][0] = (prev[0]-x0c[0])*invden;
        slopesSh[w][1] = (prev[1]-x0c[1])*invden;
        slopesSh[w][2] = (prev[2]-x0c[2])*invden;
        slopesSh[w][3] = 0.5f*(am01-am10)*invden;
        slopesSh[w][4] = 0.5f*(am02-am20)*invden;
        slopesSh[w][5] = 0.5f*(am12-am21)*invden;
    }

    // ---- h0 = init_mlp(x[b,0,:]) (one-time, fp32, global-streamed) ----
    if (tid < 128) {
        const float xv0 = x[(size_t)b*TT*3+0];
        const float xv1 = x[(size_t)b*TT*3+1];
        const float xv2 = x[(size_t)b*TT*3+2];
        float acc = b0[tid] + W0[tid*3]*xv0 + W0[tid*3+1]*xv1 + W0[tid*3+2]*xv2;
        sig0Sh[tid] = softplus_f(acc);   // reuse as scratch for a0
    }
    __syncthreads();
    if (tid < 128) {
        float acc = b1[tid];
        const float4* r = (const float4*)(W1 + tid*128);
        #pragma unroll 8
        for (int k=0;k<32;k++){ float4 wv=r[k]; float4 av=*(const float4*)&sig0Sh[4*k]; DOT4(acc,wv,av); }
        sig1Sh[tid] = softplus_f(acc);   // scratch for a1
    }
    __syncthreads();
    if (tid < 64) {
        float acc = b2[tid];
        const float4* r = (const float4*)(W2 + tid*128);
        #pragma unroll 8
        for (int k=0;k<32;k++){ float4 wv=r[k]; float4 av=*(const float4*)&sig1Sh[4*k]; DOT4(acc,wv,av); }
        ySh[tid] = acc;
    }
    __syncthreads();

    // ---- F(y): fp32 feedback path, fp16 within-step ----
    auto Feval = [&](const float* yIn, bool first, float dt, int w) {
        // S1 (fp32): z0 = V0@y + c0
        {
            float zA=0.f, zB=0.f;
            const float4* yb = (const float4*)(yIn + half*32);
            #pragma unroll
            for (int k=0;k<4;k++){ DOT4(zA, v0f[k], yb[k]); }
            #pragma unroll
            for (int k=4;k<8;k++){ DOT4(zB, v0f[k], yb[k]); }
            float z = zA + zB;
            z += __shfl_xor(z, 1, 64);
            z += c0r;
            if (!half){
                float a = softplus_f(z);
                sig0Sh[row2] = sigmoid_f(z);
                ((_Float16*)a0p)[row2] = (_Float16)a;
            }
        }
        __syncthreads();
        // S2 (f16): z1 = V1@a0 + c1
        {
            float zA=0.f, zB=0.f;
            const float4* ab = (const float4*)a0p + half*8;
            #pragma unroll
            for (int k=0;k<4;k++){ zA=dot2q(v1p4[k],ab[k],zA); }
            #pragma unroll
            for (int k=4;k<8;k++){ zB=dot2q(v1p4[k],ab[k],zB); }
            float z = zA + zB;
            z += __shfl_xor(z, 1, 64);
            z += c1r;
            if (!half){
                float a = softplus_f(z);
                sig1Sh[row2] = sigmoid_f(z);
                ((_Float16*)a1p)[row2] = (_Float16)a;
            }
        }
        __syncthreads();
        // S3 (f16): z2 = V2@a1 + c2 ; m = tanh, dtan = 1-m^2   (128 half-split + 64 quarter-split)
        {
            float zA=0.f, zB=0.f;
            const float4* ab = (const float4*)a1p + half*8;
            #pragma unroll
            for (int k=0;k<4;k++){ zA=dot2q(v2p4[k],ab[k],zA); }
            #pragma unroll
            for (int k=4;k<8;k++){ zB=dot2q(v2p4[k],ab[k],zB); }
            float z = zA + zB;
            z += __shfl_xor(z, 1, 64);
            z += c2a;
            if (!half){
                float mm=tanh_f(z); mSh[row2]=mm; dtanSh[row2]=1.f-mm*mm;
                ((_Float16*)mp)[row2]=(_Float16)mm;
            }
            float zq = 0.f;
            const float4* a4 = (const float4*)a1p;
            #pragma unroll
            for (int j=0;j<4;j++){ zq=dot2q(v2q4[j], a4[quad*4 + ((quad+j)&3)], zq); }
            zq += __shfl_xor(zq, 1, 64);
            zq += __shfl_xor(zq, 2, 64);
            zq += c2b;
            if (!quad){
                float mm=tanh_f(zq); mSh[row4]=mm; dtanSh[row4]=1.f-mm*mm;
                ((_Float16*)mp)[row4]=(_Float16)mm;
            }
        }
        __syncthreads();
        // S4 (f16): u0[d] = sig0 * (V0 @ m[d])
        {
            float t0=0.f,t1=0.f,t2=0.f;
            const float4* m0 = (const float4*)mp + half*4;
            const float4* m1 = (const float4*)mp + 8  + half*4;
            const float4* m2 = (const float4*)mp + 16 + half*4;
            #pragma unroll
            for (int k=0;k<4;k++){ t0=dot2q(v0p4[k],m0[k],t0); t1=dot2q(v0p4[k],m1[k],t1); t2=dot2q(v0p4[k],m2[k],t2); }
            t0 += __shfl_xor(t0,1,64);
            t1 += __shfl_xor(t1,1,64);
            t2 += __shfl_xor(t2,1,64);
            if (!half){
                float sg = sig0Sh[row2];
                ((_Float16*)&u0p[0][0])[row2]=(_Float16)(sg*t0);
                ((_Float16*)&u0p[1][0])[row2]=(_Float16)(sg*t1);
                ((_Float16*)&u0p[2][0])[row2]=(_Float16)(sg*t2);
            }
        }
        __syncthreads();
        // S5 (f16): u1[d] = sig1 * (V1 @ u0[d])
        {
            float t0=0.f,t1=0.f,t2=0.f;
            const float4* q0 = (const float4*)&u0p[0][0] + half*8;
            const float4* q1 = (const float4*)&u0p[1][0] + half*8;
            const float4* q2 = (const float4*)&u0p[2][0] + half*8;
            #pragma unroll
            for (int k=0;k<8;k++){ t0=dot2q(v1p4[k],q0[k],t0); t1=dot2q(v1p4[k],q1[k],t1); t2=dot2q(v1p4[k],q2[k],t2); }
            t0 += __shfl_xor(t0,1,64);
            t1 += __shfl_xor(t1,1,64);
            t2 += __shfl_xor(t2,1,64);
            if (!half){
                float sg = sig1Sh[row2];
                ((_Float16*)&u1p[0][0])[row2]=(_Float16)(sg*t0);
                ((_Float16*)&u1p[1][0])[row2]=(_Float16)(sg*t1);
                ((_Float16*)&u1p[2][0])[row2]=(_Float16)(sg*t2);
            }
        }
        __syncthreads();
        // S6 (f16): Jf[d] = dtan * (V2 @ u1[d])
        {
            float t0=0.f,t1=0.f,t2=0.f;
            const float4* q0 = (const float4*)&u1p[0][0] + half*8;
            const float4* q1 = (const float4*)&u1p[1][0] + half*8;
            const float4* q2 = (const float4*)&u1p[2][0] + half*8;
            #pragma unroll
            for (int k=0;k<8;k++){ t0=dot2q(v2p4[k],q0[k],t0); t1=dot2q(v2p4[k],q1[k],t1); t2=dot2q(v2p4[k],q2[k],t2); }
            t0 += __shfl_xor(t0,1,64);
            t1 += __shfl_xor(t1,1,64);
            t2 += __shfl_xor(t2,1,64);
            if (!half){
                float dd = dtanSh[row2];
                JfSh[0][row2]=dd*t0; JfSh[1][row2]=dd*t1; JfSh[2][row2]=dd*t2;
            }
            float s0=0.f,s1=0.f,s2=0.f;
            const float4* w0 = (const float4*)&u1p[0][0];
            const float4* w1 = (const float4*)&u1p[1][0];
            const float4* w2 = (const float4*)&u1p[2][0];
            #pragma unroll
            for (int j=0;j<4;j++){
                const int idx = quad*4 + ((quad+j)&3);
                s0=dot2q(v2q4[j],w0[idx],s0); s1=dot2q(v2q4[j],w1[idx],s1); s2=dot2q(v2q4[j],w2[idx],s2);
            }
            s0 += __shfl_xor(s0,1,64); s0 += __shfl_xor(s0,2,64);
            s1 += __shfl_xor(s1,1,64); s1 += __shfl_xor(s1,2,64);
            s2 += __shfl_xor(s2,1,64); s2 += __shfl_xor(s2,2,64);
            if (!quad){
                float dd = dtanSh[row4];
                JfSh[0][row4]=dd*s0; JfSh[1][row4]=dd*s1; JfSh[2][row4]=dd*s2;
            }
        }
        __syncthreads();
        // S7 + Heun integrate (fp32)
        if (tid < 64) {
            const int h = tid;
            const float s0=slopesSh[w][0], s1=slopesSh[w][1], s2=slopesSh[w][2],
                        s3=slopesSh[w][3], s4=slopesSh[w][4], s5=slopesSh[w][5];
            float kk = mSh[h]*s0 + mSh[64+h]*s1 + mSh[128+h]*s2;
            kk += s3*(JfSh[0][64+h]  - JfSh[1][h]);
            kk += s4*(JfSh[0][128+h] - JfSh[2][h]);
            kk += s5*(JfSh[1][128+h] - JfSh[2][64+h]);
            if (first){ k1Sh[h] = kk; y2Sh[h] = ySh[h] + dt*kk; }
            else      { ySh[h] = ySh[h] + 0.5f*dt*(k1Sh[h] + kk); }
        }
        __syncthreads();
    };

    // ---- Heun scan; projection of y_step overlapped with S1 phase ----
    for (int step=0; step<NSTEP; ++step) {
        {
            float pacc = 0.f;
            const float4* rr = (const float4*)(RSh + prow*64 + poct*8);
            const float4* yy = (const float4*)(ySh + poct*8);
            DOT4(pacc, rr[0], yy[0]); DOT4(pacc, rr[1], yy[1]);
            pacc += __shfl_xor(pacc,1,64);
            pacc += __shfl_xor(pacc,2,64);
            pacc += __shfl_xor(pacc,4,64);
            if (!poct) out[(size_t)(b*TT + step)*OUTD + prow] = tanh_f(pacc + rbp);
        }
        const float dt = dtsSh[step];
        const int w = step >> 3;
        Feval(ySh,  true,  dt, w);
        Feval(y2Sh, false, dt, w);
    }
    {
        float pacc = 0.f;
        const float4* rr = (const float4*)(RSh + prow*64 + poct*8);
        const float4* yy = (const float4*)(ySh + poct*8);
        DOT4(pacc, rr[0], yy[0]); DOT4(pacc, rr[1], yy[1]);
        pacc += __shfl_xor(pacc,1,64);
        pacc += __shfl_xor(pacc,2,64);
        pacc += __shfl_xor(pacc,4,64);
        if (!poct) out[(size_t)(b*TT + NSTEP)*OUTD + prow] = tanh_f(pacc + rbp);
    }
}

extern "C" void kernel_launch(void* const* d_in, const int* in_sizes, int n_in,
                              void* d_out, int out_size, void* d_ws, size_t ws_size,
                              hipStream_t stream) {
    const float* ts = (const float*)d_in[0];
    const float* x  = (const float*)d_in[1];
    const float* W0 = (const float*)d_in[2];
    const float* b0 = (const float*)d_in[3];
    const float* W1 = (const float*)d_in[4];
    const float* b1 = (const float*)d_in[5];
    const float* W2 = (const float*)d_in[6];
    const float* b2 = (const float*)d_in[7];
    const float* V0 = (const float*)d_in[8];
    const float* c0 = (const float*)d_in[9];
    const float* V1 = (const float*)d_in[10];
    const float* c1 = (const float*)d_in[11];
    const float* V2 = (const float*)d_in[12];
    const float* c2 = (const float*)d_in[13];
    const float* R  = (const float*)d_in[14];
    const float* rb = (const float*)d_in[15];
    float* out = (float*)d_out;

    ncde_solve<<<dim3(BB), dim3(256), 0, stream>>>(
        ts, x, W0, b0, W1, b1, W2, b2, V0, c0, V1, c1, V2, c2, R, rb, out);
}

// Round 7
// 873.756 us; speedup vs baseline: 2.7297x; 1.0390x over previous
//
#include <hip/hip_runtime.h>
#include <math.h>

// Problem constants: D=3, H=64, WIN=8, OUT=32, B=128, T=129
#define BB 128
#define TT 129
#define NSTEP 128
#define NW 16
#define WINW 8
#define OUTD 32

typedef _Float16 h2_t __attribute__((ext_vector_type(2)));

__device__ __forceinline__ float fast_rcp(float v){ return __builtin_amdgcn_rcpf(v); }
__device__ __forceinline__ float softplus_f(float v){ return fmaxf(v,0.f)+__logf(1.f+__expf(-fabsf(v))); }
__device__ __forceinline__ float sigmoid_f(float v){ return fast_rcp(1.f+__expf(-v)); }
__device__ __forceinline__ float tanh_f(float v){
    float ax=fminf(fabsf(v),15.f); float e=__expf(2.f*ax);
    float r=1.f-2.f*fast_rcp(e+1.f); return copysignf(r,v);
}
__device__ __forceinline__ float pack2(float a,float b){
    h2_t h; h.x=(_Float16)a; h.y=(_Float16)b; return __builtin_bit_cast(float,h);
}
__device__ __forceinline__ float dot2c(float wc,float ac,float acc){
    return __builtin_amdgcn_fdot2(__builtin_bit_cast(h2_t,wc),__builtin_bit_cast(h2_t,ac),acc,false);
}
__device__ __forceinline__ float dot2q(float4 wq,float4 aq,float acc){
    acc=dot2c(wq.x,aq.x,acc); acc=dot2c(wq.y,aq.y,acc);
    acc=dot2c(wq.z,aq.z,acc); acc=dot2c(wq.w,aq.w,acc); return acc;
}
#define DOT4(acc,Wv,Av) acc += (Wv).x*(Av).x + (Wv).y*(Av).y + (Wv).z*(Av).z + (Wv).w*(Av).w
#define PIN4(q) asm volatile("" : "+v"((q).x), "+v"((q).y), "+v"((q).z), "+v"((q).w))

__global__ __launch_bounds__(256, 1)
void ncde_solve(const float* __restrict__ ts, const float* __restrict__ x,
                const float* __restrict__ W0, const float* __restrict__ b0,
                const float* __restrict__ W1, const float* __restrict__ b1,
                const float* __restrict__ W2, const float* __restrict__ b2,
                const float* __restrict__ V0, const float* __restrict__ c0,
                const float* __restrict__ V1, const float* __restrict__ c1,
                const float* __restrict__ V2, const float* __restrict__ c2,
                const float* __restrict__ R, const float* __restrict__ rb,
                float* __restrict__ out)
{
    const int b = blockIdx.x;
    const int tid = threadIdx.x;
    const int row2 = tid >> 1, half = tid & 1;         // rows 0..127, K halved
    const int row4 = 128 + (tid >> 2), quad = tid & 3; // V2 rows 128..191, K quartered
    const int prow = tid >> 3, poct = tid & 7;         // projection

    __shared__ __align__(16) float RSh[OUTD*64];
    __shared__ __align__(16) float ySh[64], k1Sh[64];
    __shared__ __align__(16) float yp[32], y2p[32];        // y: 64 packed halves
    __shared__ __align__(16) float a0p[64], a1p[64];       // a0,a1: 128 packed halves each
    __shared__ __align__(16) float mp[96];                 // m: 192 packed halves
    __shared__ __align__(16) float u0p[3][64], u1p[3][64]; // u0,u1: 128 packed halves each
    __shared__ float mSh[192];
    __shared__ float JfSh[3][192];
    __shared__ float slopesSh[NW][6];
    __shared__ float dtsSh[NSTEP];

    // ---- fp16-packed weight carriers in registers: 24 float4 = 96 VGPRs ----
    float4 v0p4[4];  // V0 half-row  (32 halves)
    float4 v1p4[8];  // V1 half-row  (64 halves)
    float4 v2p4[8];  // V2 rows 0..127 half-row (64 halves)
    float4 v2q4[4];  // V2 rows 128..191 quarter-row (32 halves), rotated groups
    {
        const float4* p0 = (const float4*)(V0 + row2*64 + half*32);
        #pragma unroll
        for (int k=0;k<4;k++){
            float4 a=p0[2*k], c=p0[2*k+1];
            float4 r; r.x=pack2(a.x,a.y); r.y=pack2(a.z,a.w); r.z=pack2(c.x,c.y); r.w=pack2(c.z,c.w);
            v0p4[k]=r;
        }
        const float4* p1 = (const float4*)(V1 + row2*128 + half*64);
        #pragma unroll
        for (int k=0;k<8;k++){
            float4 a=p1[2*k], c=p1[2*k+1];
            float4 r; r.x=pack2(a.x,a.y); r.y=pack2(a.z,a.w); r.z=pack2(c.x,c.y); r.w=pack2(c.z,c.w);
            v1p4[k]=r;
        }
        const float4* p2 = (const float4*)(V2 + row2*128 + half*64);
        #pragma unroll
        for (int k=0;k<8;k++){
            float4 a=p2[2*k], c=p2[2*k+1];
            float4 r; r.x=pack2(a.x,a.y); r.y=pack2(a.z,a.w); r.z=pack2(c.x,c.y); r.w=pack2(c.z,c.w);
            v2p4[k]=r;
        }
        #pragma unroll
        for (int j=0;j<4;j++){
            int g=(quad+j)&3;
            const float4* pg = (const float4*)(V2 + row4*128 + quad*32 + g*8);
            float4 a=pg[0], c=pg[1];
            float4 r; r.x=pack2(a.x,a.y); r.y=pack2(a.z,a.w); r.z=pack2(c.x,c.y); r.w=pack2(c.z,c.w);
            v2q4[j]=r;
        }
        #pragma unroll
        for (int k=0;k<4;k++) PIN4(v0p4[k]);
        #pragma unroll
        for (int k=0;k<8;k++) PIN4(v1p4[k]);
        #pragma unroll
        for (int k=0;k<8;k++) PIN4(v2p4[k]);
        #pragma unroll
        for (int k=0;k<4;k++) PIN4(v2q4[k]);
    }
    const float c0r = c0[row2], c1r = c1[row2], c2a = c2[row2], c2b = c2[row4];
    const float rbp = rb[prow];

    for (int i=tid; i<OUTD*64; i+=256) RSh[i] = R[i];
    const float* tsb = ts + b*TT;
    for (int i=tid; i<NSTEP; i+=256) dtsSh[i] = tsb[i+1] - tsb[i];

    // ---- log-signature slopes ----
    if (tid < NW) {
        const int w = tid;
        const float* xs = x + (size_t)(b*TT + w*WINW)*3;
        float x0c[3] = {xs[0], xs[1], xs[2]};
        float prev[3] = {x0c[0], x0c[1], x0c[2]};
        float am01=0.f, am02=0.f, am12=0.f, am10=0.f, am20=0.f, am21=0.f;
        #pragma unroll
        for (int k=0;k<WINW;k++) {
            float cur[3] = {xs[(k+1)*3+0], xs[(k+1)*3+1], xs[(k+1)*3+2]};
            float rel[3], dv[3];
            #pragma unroll
            for (int c=0;c<3;c++){ rel[c]=prev[c]-x0c[c]; dv[c]=cur[c]-prev[c]; }
            am01 += rel[0]*dv[1]; am10 += rel[1]*dv[0];
            am02 += rel[0]*dv[2]; am20 += rel[2]*dv[0];
            am12 += rel[1]*dv[2]; am21 += rel[2]*dv[1];
            prev[0]=cur[0]; prev[1]=cur[1]; prev[2]=cur[2];
        }
        const float invden = 1.f/(tsb[(w+1)*WINW] - tsb[w*WINW]);
        slopesSh[w][0] = (prev[0]-x0c[0])*invden;
        slopesSh[w][1] = (prev[1]-x0c[1])*invden;
        slopesSh[w][2] = (prev[2]-x0c[2])*invden;
        slopesSh[w][3] = 0.5f*(am01-am10)*invden;
        slopesSh[w][4] = 0.5f*(am02-am20)*invden;
        slopesSh[w][5] = 0.5f*(am12-am21)*invden;
    }

    // ---- h0 = init_mlp(x[b,0,:]) (one-time, fp32, global-streamed; mSh/JfSh as scratch) ----
    if (tid < 128) {
        const float xv0 = x[(size_t)b*TT*3+0];
        const float xv1 = x[(size_t)b*TT*3+1];
        const float xv2 = x[(size_t)b*TT*3+2];
        float acc = b0[tid] + W0[tid*3]*xv0 + W0[tid*3+1]*xv1 + W0[tid*3+2]*xv2;
        mSh[tid] = softplus_f(acc);
    }
    __syncthreads();
    if (tid < 128) {
        float acc = b1[tid];
        const float4* r = (const float4*)(W1 + tid*128);
        #pragma unroll 8
        for (int k=0;k<32;k++){ float4 wv=r[k]; float4 av=*(const float4*)&mSh[4*k]; DOT4(acc,wv,av); }
        JfSh[0][tid] = softplus_f(acc);
    }
    __syncthreads();
    if (tid < 64) {
        float acc = b2[tid];
        const float4* r = (const float4*)(W2 + tid*128);
        #pragma unroll 8
        for (int k=0;k<32;k++){ float4 wv=r[k]; float4 av=*(const float4*)&JfSh[0][4*k]; DOT4(acc,wv,av); }
        ySh[tid] = acc;
        float p = __shfl_xor(acc, 1, 64);
        if (!(tid & 1)) yp[tid>>1] = pack2(acc, p);
    }
    __syncthreads();

    // per-lane activation-derivative registers (producer lane == consumer lane)
    float sig0r=0.f, sig1r=0.f, dtanAr=0.f, dtanBr=0.f;

    // ---- F(y): fp16 inner, fp32 feedback (y, k, S7 combine) ----
    auto Feval = [&](const float* ypIn, bool first, float dt, int w) {
        // S1: z0 = V0@y + c0  (fp16, y carriers: 8 f4; half picks 4)
        {
            float zA=0.f, zB=0.f;
            const float4* yb = (const float4*)ypIn + half*4;
            zA=dot2q(v0p4[0],yb[0],zA); zB=dot2q(v0p4[1],yb[1],zB);
            zA=dot2q(v0p4[2],yb[2],zA); zB=dot2q(v0p4[3],yb[3],zB);
            float z = zA + zB;
            z += __shfl_xor(z, 1, 64);
            z += c0r;
            float a = softplus_f(z);
            sig0r = sigmoid_f(z);
            if (!half) ((_Float16*)a0p)[row2] = (_Float16)a;
        }
        __syncthreads();
        // S2: z1 = V1@a0 + c1  (a0: 16 f4 carriers; half picks 8)
        {
            float zA=0.f, zB=0.f;
            const float4* ab = (const float4*)a0p + half*8;
            #pragma unroll
            for (int k=0;k<4;k++){ zA=dot2q(v1p4[k],ab[k],zA); }
            #pragma unroll
            for (int k=4;k<8;k++){ zB=dot2q(v1p4[k],ab[k],zB); }
            float z = zA + zB;
            z += __shfl_xor(z, 1, 64);
            z += c1r;
            float a = softplus_f(z);
            sig1r = sigmoid_f(z);
            if (!half) ((_Float16*)a1p)[row2] = (_Float16)a;
        }
        __syncthreads();
        // S3: z2 = V2@a1 + c2 ; m = tanh, dtan in regs (128 half-split + 64 quarter-split)
        {
            float zA=0.f, zB=0.f;
            const float4* ab = (const float4*)a1p + half*8;
            #pragma unroll
            for (int k=0;k<4;k++){ zA=dot2q(v2p4[k],ab[k],zA); }
            #pragma unroll
            for (int k=4;k<8;k++){ zB=dot2q(v2p4[k],ab[k],zB); }
            float z = zA + zB;
            z += __shfl_xor(z, 1, 64);
            z += c2a;
            float mm = tanh_f(z);
            dtanAr = 1.f - mm*mm;
            if (!half){ mSh[row2]=mm; ((_Float16*)mp)[row2]=(_Float16)mm; }

            float zq = 0.f;
            const float4* a4 = (const float4*)a1p;
            #pragma unroll
            for (int j=0;j<4;j++){ zq=dot2q(v2q4[j], a4[quad*4 + ((quad+j)&3)], zq); }
            zq += __shfl_xor(zq, 1, 64);
            zq += __shfl_xor(zq, 2, 64);
            zq += c2b;
            float mq = tanh_f(zq);
            dtanBr = 1.f - mq*mq;
            if (!quad){ mSh[row4]=mq; ((_Float16*)mp)[row4]=(_Float16)mq; }
        }
        __syncthreads();
        // S4: u0[d] = sig0 * (V0 @ m[d])  (m[d]: 8 f4 carriers per d; half picks 4)
        {
            float t0=0.f,t1=0.f,t2=0.f;
            const float4* m0 = (const float4*)mp + half*4;
            const float4* m1 = (const float4*)mp + 8  + half*4;
            const float4* m2 = (const float4*)mp + 16 + half*4;
            #pragma unroll
            for (int k=0;k<4;k++){ t0=dot2q(v0p4[k],m0[k],t0); t1=dot2q(v0p4[k],m1[k],t1); t2=dot2q(v0p4[k],m2[k],t2); }
            t0 += __shfl_xor(t0,1,64);
            t1 += __shfl_xor(t1,1,64);
            t2 += __shfl_xor(t2,1,64);
            if (!half){
                ((_Float16*)&u0p[0][0])[row2]=(_Float16)(sig0r*t0);
                ((_Float16*)&u0p[1][0])[row2]=(_Float16)(sig0r*t1);
                ((_Float16*)&u0p[2][0])[row2]=(_Float16)(sig0r*t2);
            }
        }
        __syncthreads();
        // S5: u1[d] = sig1 * (V1 @ u0[d])  (u0[d]: 16 f4; half picks 8)
        {
            float t0=0.f,t1=0.f,t2=0.f;
            const float4* q0 = (const float4*)&u0p[0][0] + half*8;
            const float4* q1 = (const float4*)&u0p[1][0] + half*8;
            const float4* q2 = (const float4*)&u0p[2][0] + half*8;
            #pragma unroll
            for (int k=0;k<8;k++){ t0=dot2q(v1p4[k],q0[k],t0); t1=dot2q(v1p4[k],q1[k],t1); t2=dot2q(v1p4[k],q2[k],t2); }
            t0 += __shfl_xor(t0,1,64);
            t1 += __shfl_xor(t1,1,64);
            t2 += __shfl_xor(t2,1,64);
            if (!half){
                ((_Float16*)&u1p[0][0])[row2]=(_Float16)(sig1r*t0);
                ((_Float16*)&u1p[1][0])[row2]=(_Float16)(sig1r*t1);
                ((_Float16*)&u1p[2][0])[row2]=(_Float16)(sig1r*t2);
            }
        }
        __syncthreads();
        // S6: Jf[d] = dtan * (V2 @ u1[d])
        {
            float t0=0.f,t1=0.f,t2=0.f;
            const float4* q0 = (const float4*)&u1p[0][0] + half*8;
            const float4* q1 = (const float4*)&u1p[1][0] + half*8;
            const float4* q2 = (const float4*)&u1p[2][0] + half*8;
            #pragma unroll
            for (int k=0;k<8;k++){ t0=dot2q(v2p4[k],q0[k],t0); t1=dot2q(v2p4[k],q1[k],t1); t2=dot2q(v2p4[k],q2[k],t2); }
            t0 += __shfl_xor(t0,1,64);
            t1 += __shfl_xor(t1,1,64);
            t2 += __shfl_xor(t2,1,64);
            if (!half){
                JfSh[0][row2]=dtanAr*t0; JfSh[1][row2]=dtanAr*t1; JfSh[2][row2]=dtanAr*t2;
            }
            float s0=0.f,s1=0.f,s2=0.f;
            const float4* w0 = (const float4*)&u1p[0][0];
            const float4* w1 = (const float4*)&u1p[1][0];
            const float4* w2 = (const float4*)&u1p[2][0];
            #pragma unroll
            for (int j=0;j<4;j++){
                const int idx = quad*4 + ((quad+j)&3);
                s0=dot2q(v2q4[j],w0[idx],s0); s1=dot2q(v2q4[j],w1[idx],s1); s2=dot2q(v2q4[j],w2[idx],s2);
            }
            s0 += __shfl_xor(s0,1,64); s0 += __shfl_xor(s0,2,64);
            s1 += __shfl_xor(s1,1,64); s1 += __shfl_xor(s1,2,64);
            s2 += __shfl_xor(s2,1,64); s2 += __shfl_xor(s2,2,64);
            if (!quad){
                JfSh[0][row4]=dtanBr*s0; JfSh[1][row4]=dtanBr*s1; JfSh[2][row4]=dtanBr*s2;
            }
        }
        __syncthreads();
        // S7 + Heun integrate (fp32, wave 0) + fp16 y re-pack via shfl
        if (tid < 64) {
            const int h = tid;
            const float s0=slopesSh[w][0], s1=slopesSh[w][1], s2=slopesSh[w][2],
                        s3=slopesSh[w][3], s4=slopesSh[w][4], s5=slopesSh[w][5];
            float kk = mSh[h]*s0 + mSh[64+h]*s1 + mSh[128+h]*s2;
            kk += s3*(JfSh[0][64+h]  - JfSh[1][h]);
            kk += s4*(JfSh[0][128+h] - JfSh[2][h]);
            kk += s5*(JfSh[1][128+h] - JfSh[2][64+h]);
            if (first){
                k1Sh[h] = kk;
                float y2 = ySh[h] + dt*kk;
                float p = __shfl_xor(y2, 1, 64);
                if (!(h&1)) y2p[h>>1] = pack2(y2, p);
            } else {
                float yn = ySh[h] + 0.5f*dt*(k1Sh[h] + kk);
                ySh[h] = yn;
                float p = __shfl_xor(yn, 1, 64);
                if (!(h&1)) yp[h>>1] = pack2(yn, p);
            }
        }
        __syncthreads();
    };

    // ---- Heun scan; projection of y_step overlapped with S1 phase ----
    for (int step=0; step<NSTEP; ++step) {
        {
            float pacc = 0.f;
            const float4* rr = (const float4*)(RSh + prow*64 + poct*8);
            const float4* yy = (const float4*)(ySh + poct*8);
            DOT4(pacc, rr[0], yy[0]); DOT4(pacc, rr[1], yy[1]);
            pacc += __shfl_xor(pacc,1,64);
            pacc += __shfl_xor(pacc,2,64);
            pacc += __shfl_xor(pacc,4,64);
            if (!poct) out[(size_t)(b*TT + step)*OUTD + prow] = tanh_f(pacc + rbp);
        }
        const float dt = dtsSh[step];
        const int w = step >> 3;
        Feval(yp,  true,  dt, w);
        Feval(y2p, false, dt, w);
    }
    {
        float pacc = 0.f;
        const float4* rr = (const float4*)(RSh + prow*64 + poct*8);
        const float4* yy = (const float4*)(ySh + poct*8);
        DOT4(pacc, rr[0], yy[0]); DOT4(pacc, rr[1], yy[1]);
        pacc += __shfl_xor(pacc,1,64);
        pacc += __shfl_xor(pacc,2,64);
        pacc += __shfl_xor(pacc,4,64);
        if (!poct) out[(size_t)(b*TT + NSTEP)*OUTD + prow] = tanh_f(pacc + rbp);
    }
}

extern "C" void kernel_launch(void* const* d_in, const int* in_sizes, int n_in,
                              void* d_out, int out_size, void* d_ws, size_t ws_size,
                              hipStream_t stream) {
    const float* ts = (const float*)d_in[0];
    const float* x  = (const float*)d_in[1];
    const float* W0 = (const float*)d_in[2];
    const float* b0 = (const float*)d_in[3];
    const float* W1 = (const float*)d_in[4];
    const float* b1 = (const float*)d_in[5];
    const float* W2 = (const float*)d_in[6];
    const float* b2 = (const float*)d_in[7];
    const float* V0 = (const float*)d_in[8];
    const float* c0 = (const float*)d_in[9];
    const float* V1 = (const float*)d_in[10];
    const float* c1 = (const float*)d_in[11];
    const float* V2 = (const float*)d_in[12];
    const float* c2 = (const float*)d_in[13];
    const float* R  = (const float*)d_in[14];
    const float* rb = (const float*)d_in[15];
    float* out = (float*)d_out;

    ncde_solve<<<dim3(BB), dim3(256), 0, stream>>>(
        ts, x, W0, b0, W1, b1, W2, b2, V0, c0, V1, c1, V2, c2, R, rb, out);
}